// Round 10
// baseline (212.199 us; speedup 1.0000x reference)
//
#include <hip/hip_runtime.h>

#define HW 256
#define HWMASK 255
#define CH 128
#define BATCH 8
#define NK 4
#define STRIP 32           // rows per thread (wave = full 256-col row)
#define NIN (STRIP + 6)    // input rows touched per strip

typedef float f32x4 __attribute__((ext_vector_type(4)));

// ---------------- Kernel A1: partial sums of guidance ----------------
__global__ __launch_bounds__(256) void mean1_kernel(const float* __restrict__ guid,
                                                    float* __restrict__ partial) {
    int blk = blockIdx.x;
    const float4* p = (const float4*)(guid + (size_t)blk * 16384);
    float s = 0.f;
    for (int i = threadIdx.x; i < 4096; i += 256) {
        float4 v = p[i];
        s += (v.x + v.y) + (v.z + v.w);
    }
    for (int off = 32; off; off >>= 1) s += __shfl_down(s, off, 64);
    __shared__ float red[4];
    if ((threadIdx.x & 63) == 0) red[threadIdx.x >> 6] = s;
    __syncthreads();
    if (threadIdx.x == 0) partial[blk] = (red[0] + red[1]) + (red[2] + red[3]);
}

// ---------------- Kernel B: finalize means + MLP + softmax ----------------
__global__ __launch_bounds__(256) void mlp_kernel(const float* __restrict__ partial,
                                                  const float* __restrict__ w1,
                                                  const float* __restrict__ b1,
                                                  const float* __restrict__ w2,
                                                  const float* __restrict__ b2,
                                                  float* __restrict__ wt) {
    __shared__ float gs[BATCH * CH];
    __shared__ float h1[BATCH * 32];
    __shared__ float lg[BATCH * NK];
    int t = threadIdx.x;
    for (int i = t; i < BATCH * CH; i += 256) {
        float4 v = *(const float4*)(partial + i * 4);
        gs[i] = ((v.x + v.y) + (v.z + v.w)) * (1.0f / 65536.0f);
    }
    __syncthreads();
    {
        int b = t >> 5, j = t & 31;
        float acc = b1[j];
        #pragma unroll 4
        for (int c = 0; c < CH; ++c) acc += gs[b * CH + c] * w1[j * CH + c];
        h1[b * 32 + j] = fmaxf(acc, 0.f);
    }
    __syncthreads();
    if (t < BATCH * NK) {
        int b = t >> 2, k = t & 3;
        float acc = b2[k];
        #pragma unroll
        for (int j = 0; j < 32; ++j) acc += h1[b * 32 + j] * w2[k * 32 + j];
        lg[b * NK + k] = acc;
    }
    __syncthreads();
    if (t < BATCH) {
        int b = t;
        float m = lg[b * 4];
        for (int k = 1; k < 4; ++k) m = fmaxf(m, lg[b * 4 + k]);
        float e[4], s = 0.f;
        for (int k = 0; k < 4; ++k) { e[k] = expf(lg[b * 4 + k] - m); s += e[k]; }
        float inv = 1.0f / s;
        for (int k = 0; k < 4; ++k) wt[b * 4 + k] = e[k] * inv;
    }
}

// ---------------- Kernel C: dyn = blend of basis filters, stored FLIPPED ----------------
__global__ __launch_bounds__(256) void dyn_kernel(const float* __restrict__ wt,
                                                  const float* __restrict__ basis,
                                                  float* __restrict__ dynF) {
    int idx = blockIdx.x * 256 + threadIdx.x;
    if (idx >= BATCH * CH * 49) return;
    int ij = idx % 49;
    int bc = idx / 49;
    int c = bc % CH;
    int b = bc / CH;
    float acc = 0.f;
    #pragma unroll
    for (int k = 0; k < NK; ++k)
        acc += wt[b * NK + k] * basis[(k * CH + c) * 49 + ij];
    dynF[bc * 49 + (48 - ij)] = acc;
}

// ---------------- Kernel D: circular depthwise 7x7 conv, register sliding window ----
// No LDS, no barriers. Wave = 64 lanes x 4 cols = full 256-px row; strip = 32 rows.
// Explicit 2-deep row prefetch (pf[2][3], fully unrolled -> all reg-resident).
// Every load/store instruction touches one contiguous (wrapped) 1KB row segment.
__global__ __launch_bounds__(256, 4) void conv_kernel(const float* __restrict__ x,
                                                      const float* __restrict__ dynF,
                                                      float* __restrict__ out) {
    int bc = blockIdx.x;                  // 0..1023 plane id
    const float* xp = x + (size_t)bc * (HW * HW);
    float* op = out + (size_t)bc * (HW * HW);
    int tid = threadIdx.x;
    int lane = tid & 63, ty = tid >> 6;
    int yb = blockIdx.y * (4 * STRIP) + ty * STRIP;

    // filter taps: block-uniform address -> scalar loads into SGPRs
    const float* df = dynF + bc * 49;
    float d[49];
    #pragma unroll
    for (int i = 0; i < 49; ++i) d[i] = df[i];

    // wrapped quad offsets: cols 4*lane-4 .. 4*lane+7 (window needs 4l-3..4l+6)
    int gx0 = (4 * lane - 4) & HWMASK;
    int gx1 = (4 * lane) & HWMASK;
    int gx2 = (4 * lane + 4) & HWMASK;

    // prologue: prefetch input rows 0,1 of the window
    float4 pf[2][3];
    #pragma unroll
    for (int k = 0; k < 2; ++k) {
        const float* rp = xp + (((yb + k - 3) & HWMASK) * HW);
        pf[k][0] = *(const float4*)(rp + gx0);
        pf[k][1] = *(const float4*)(rp + gx1);
        pf[k][2] = *(const float4*)(rp + gx2);
    }

    float acc[7][4] = {};
    #pragma unroll
    for (int i = 0; i < NIN; ++i) {
        float4 A = pf[i & 1][0], B = pf[i & 1][1], C = pf[i & 1][2];
        // issue prefetch of row i+2 into the slot we just consumed
        if (i + 2 < NIN) {
            const float* rp = xp + (((yb + i - 1) & HWMASK) * HW);
            pf[i & 1][0] = *(const float4*)(rp + gx0);
            pf[i & 1][1] = *(const float4*)(rp + gx1);
            pf[i & 1][2] = *(const float4*)(rp + gx2);
        }
        float v[12] = {A.x, A.y, A.z, A.w, B.x, B.y, B.z, B.w, C.x, C.y, C.z, C.w};
        #pragma unroll
        for (int ii = 0; ii < 7; ++ii) {
            int o = i - ii;                       // output row receiving filter row ii
            if (o >= 0 && o < STRIP) {
                const int s = ((unsigned)o) % 7;  // compile-time
                #pragma unroll
                for (int q = 0; q < 4; ++q) {
                    #pragma unroll
                    for (int jj = 0; jj < 7; ++jj)
                        acc[s][q] += d[ii * 7 + jj] * v[q + jj + 1];
                }
            }
        }
        if (i >= 6) {
            const int o = i - 6;
            const int s = ((unsigned)o) % 7;
            f32x4 ov = {acc[s][0], acc[s][1], acc[s][2], acc[s][3]};
            __builtin_nontemporal_store(ov, (f32x4*)(op + (yb + o) * HW + 4 * lane));
            acc[s][0] = 0.f; acc[s][1] = 0.f; acc[s][2] = 0.f; acc[s][3] = 0.f;
        }
    }
}

extern "C" void kernel_launch(void* const* d_in, const int* in_sizes, int n_in,
                              void* d_out, int out_size, void* d_ws, size_t ws_size,
                              hipStream_t stream) {
    const float* x        = (const float*)d_in[0];
    const float* guidance = (const float*)d_in[1];
    const float* basis    = (const float*)d_in[2];
    const float* w1       = (const float*)d_in[3];
    const float* b1       = (const float*)d_in[4];
    const float* w2       = (const float*)d_in[5];
    const float* b2       = (const float*)d_in[6];
    float* out = (float*)d_out;
    float* ws  = (float*)d_ws;

    float* partial = ws;                  // 4096
    float* wt      = ws + 4096;           // 32
    float* dynF    = ws + 4096 + 32;      // 50176

    mean1_kernel<<<4096, 256, 0, stream>>>(guidance, partial);
    mlp_kernel<<<1, 256, 0, stream>>>(partial, w1, b1, w2, b2, wt);
    dyn_kernel<<<(BATCH * CH * 49 + 255) / 256, 256, 0, stream>>>(wt, basis, dynF);
    conv_kernel<<<dim3(BATCH * CH, HW / (4 * STRIP)), 256, 0, stream>>>(x, dynF, out);
}

// Round 11
// 207.846 us; speedup vs baseline: 1.0209x; 1.0209x over previous
//
#include <hip/hip_runtime.h>

#define HW 256
#define HWMASK 255
#define CH 128
#define BATCH 8
#define NK 4
#define TSY 16
#define RING 32                 // LDS ring rows (power of 2)
#define QR 66                   // float4 quads per row: cols -4..259 wrapped

typedef float f32x4 __attribute__((ext_vector_type(4)));

// ---------------- Kernel A1: partial sums of guidance ----------------
__global__ __launch_bounds__(256) void mean1_kernel(const float* __restrict__ guid,
                                                    float* __restrict__ partial) {
    int blk = blockIdx.x;
    const float4* p = (const float4*)(guid + (size_t)blk * 16384);
    float s = 0.f;
    for (int i = threadIdx.x; i < 4096; i += 256) {
        float4 v = p[i];
        s += (v.x + v.y) + (v.z + v.w);
    }
    for (int off = 32; off; off >>= 1) s += __shfl_down(s, off, 64);
    __shared__ float red[4];
    if ((threadIdx.x & 63) == 0) red[threadIdx.x >> 6] = s;
    __syncthreads();
    if (threadIdx.x == 0) partial[blk] = (red[0] + red[1]) + (red[2] + red[3]);
}

// ---------------- Kernel B: finalize means + MLP + softmax ----------------
__global__ __launch_bounds__(256) void mlp_kernel(const float* __restrict__ partial,
                                                  const float* __restrict__ w1,
                                                  const float* __restrict__ b1,
                                                  const float* __restrict__ w2,
                                                  const float* __restrict__ b2,
                                                  float* __restrict__ wt) {
    __shared__ float gs[BATCH * CH];
    __shared__ float h1[BATCH * 32];
    __shared__ float lg[BATCH * NK];
    int t = threadIdx.x;
    for (int i = t; i < BATCH * CH; i += 256) {
        float4 v = *(const float4*)(partial + i * 4);
        gs[i] = ((v.x + v.y) + (v.z + v.w)) * (1.0f / 65536.0f);
    }
    __syncthreads();
    {
        int b = t >> 5, j = t & 31;
        float acc = b1[j];
        #pragma unroll 4
        for (int c = 0; c < CH; ++c) acc += gs[b * CH + c] * w1[j * CH + c];
        h1[b * 32 + j] = fmaxf(acc, 0.f);
    }
    __syncthreads();
    if (t < BATCH * NK) {
        int b = t >> 2, k = t & 3;
        float acc = b2[k];
        #pragma unroll
        for (int j = 0; j < 32; ++j) acc += h1[b * 32 + j] * w2[k * 32 + j];
        lg[b * NK + k] = acc;
    }
    __syncthreads();
    if (t < BATCH) {
        int b = t;
        float m = lg[b * 4];
        for (int k = 1; k < 4; ++k) m = fmaxf(m, lg[b * 4 + k]);
        float e[4], s = 0.f;
        for (int k = 0; k < 4; ++k) { e[k] = expf(lg[b * 4 + k] - m); s += e[k]; }
        float inv = 1.0f / s;
        for (int k = 0; k < 4; ++k) wt[b * 4 + k] = e[k] * inv;
    }
}

// ---------------- Kernel C: dyn = blend of basis filters, stored FLIPPED ----------------
__global__ __launch_bounds__(256) void dyn_kernel(const float* __restrict__ wt,
                                                  const float* __restrict__ basis,
                                                  float* __restrict__ dynF) {
    int idx = blockIdx.x * 256 + threadIdx.x;
    if (idx >= BATCH * CH * 49) return;
    int ij = idx % 49;
    int bc = idx / 49;
    int c = bc % CH;
    int b = bc / CH;
    float acc = 0.f;
    #pragma unroll
    for (int k = 0; k < NK; ++k)
        acc += wt[b * NK + k] * basis[(k * CH + c) * 49 + ij];
    dynF[bc * 49 + (48 - ij)] = acc;
}

// ---------------- Kernel D: circular depthwise 7x7 conv, persistent ring buffer ----
// One block per (b,c) plane (1024 blocks = 4/CU resident). LDS ring of 32 rows
// (33.8 KB). Per 16-row tile: issue next-tile global loads to regs (issue-early),
// compute from ring, store, barrier, ds_write staged rows (write-late), barrier.
// Each input row staged exactly once -> no vertical halo re-read.
__global__ __launch_bounds__(256, 4) void conv_kernel(const float* __restrict__ x,
                                                      const float* __restrict__ dynF,
                                                      float* __restrict__ out) {
    int bc = blockIdx.x;                  // 0..1023 plane id
    const float* xp = x + (size_t)bc * (HW * HW);
    float* op = out + (size_t)bc * (HW * HW);
    int tid = threadIdx.x;
    int tx = tid & 63, ty = tid >> 6;

    __shared__ float4 lds4[RING * QR];    // ring row r -> slot (r & 31)

    // filter taps: block-uniform address -> scalar loads into SGPRs
    const float* df = dynF + bc * 49;
    float d[49];
    #pragma unroll
    for (int i = 0; i < 49; ++i) d[i] = df[i];

    // prologue: stage window(0) = rows -3..18 (22 rows x 66 quads = 1452 quads)
    #pragma unroll
    for (int k = 0; k < 6; ++k) {
        int e = (k < 5) ? k * 256 + tid : 1196 + tid;   // last chunk overlaps (dup-safe)
        int r = e / 66 - 3;
        int q = e - (r + 3) * 66;
        lds4[(r & 31) * QR + q] = *(const float4*)(xp + (r & HWMASK) * HW + ((4 * q - 4) & HWMASK));
    }
    __syncthreads();

    #pragma unroll 1
    for (int t = 0; t < 16; ++t) {
        // ---- issue-early: global loads for stage(t+1) = rows 16t+19 .. 16t+34 ----
        float4 pf0, pf1, pf2, pf3, pf4;
        int l0, l1, l2, l3, l4;
        if (t < 15) {
            int rb = 16 * t + 19;
            { int e = tid;              int ro = e / 66; int q = e - ro * 66; int r = rb + ro;
              pf0 = *(const float4*)(xp + (r & HWMASK) * HW + ((4 * q - 4) & HWMASK)); l0 = (r & 31) * QR + q; }
            { int e = 256 + tid;        int ro = e / 66; int q = e - ro * 66; int r = rb + ro;
              pf1 = *(const float4*)(xp + (r & HWMASK) * HW + ((4 * q - 4) & HWMASK)); l1 = (r & 31) * QR + q; }
            { int e = 512 + tid;        int ro = e / 66; int q = e - ro * 66; int r = rb + ro;
              pf2 = *(const float4*)(xp + (r & HWMASK) * HW + ((4 * q - 4) & HWMASK)); l2 = (r & 31) * QR + q; }
            { int e = 768 + tid;        int ro = e / 66; int q = e - ro * 66; int r = rb + ro;
              pf3 = *(const float4*)(xp + (r & HWMASK) * HW + ((4 * q - 4) & HWMASK)); l3 = (r & 31) * QR + q; }
            { int e = 1024 + (tid & 31); int ro = e / 66; int q = e - ro * 66; int r = rb + ro;
              pf4 = *(const float4*)(xp + (r & HWMASK) * HW + ((4 * q - 4) & HWMASK)); l4 = (r & 31) * QR + q; }
        }

        // ---- compute tile t from ring window [16t-3, 16t+18] ----
        int y0 = 16 * t + 4 * ty;
        float acc[4][4] = {};
        #pragma unroll
        for (int rr = 0; rr < 10; ++rr) {
            int r = y0 + rr - 3;
            const float4* rp = &lds4[(r & 31) * QR + tx];
            float4 A = rp[0], B = rp[1], C = rp[2];
            float v[12] = {A.x, A.y, A.z, A.w, B.x, B.y, B.z, B.w, C.x, C.y, C.z, C.w};
            #pragma unroll
            for (int rq = 0; rq < 4; ++rq) {
                int ii = rr - rq;
                if (ii >= 0 && ii <= 6) {
                    #pragma unroll
                    for (int q = 0; q < 4; ++q) {
                        #pragma unroll
                        for (int jj = 0; jj < 7; ++jj)
                            acc[rq][q] += d[ii * 7 + jj] * v[q + jj + 1];
                    }
                }
            }
        }
        #pragma unroll
        for (int rq = 0; rq < 4; ++rq) {
            f32x4 o = {acc[rq][0], acc[rq][1], acc[rq][2], acc[rq][3]};
            __builtin_nontemporal_store(o, (f32x4*)(op + (y0 + rq) * HW + 4 * tx));
        }

        // ---- all waves done reading window(t) ----
        asm volatile("" ::: "memory");
        __builtin_amdgcn_s_barrier();
        asm volatile("" ::: "memory");

        // ---- write-late: commit staged rows into ring ----
        if (t < 15) {
            lds4[l0] = pf0;
            lds4[l1] = pf1;
            lds4[l2] = pf2;
            lds4[l3] = pf3;
            lds4[l4] = pf4;
        }
        asm volatile("s_waitcnt lgkmcnt(0)" ::: "memory");
        __builtin_amdgcn_s_barrier();
        asm volatile("" ::: "memory");
    }
}

extern "C" void kernel_launch(void* const* d_in, const int* in_sizes, int n_in,
                              void* d_out, int out_size, void* d_ws, size_t ws_size,
                              hipStream_t stream) {
    const float* x        = (const float*)d_in[0];
    const float* guidance = (const float*)d_in[1];
    const float* basis    = (const float*)d_in[2];
    const float* w1       = (const float*)d_in[3];
    const float* b1       = (const float*)d_in[4];
    const float* w2       = (const float*)d_in[5];
    const float* b2       = (const float*)d_in[6];
    float* out = (float*)d_out;
    float* ws  = (float*)d_ws;

    float* partial = ws;                  // 4096
    float* wt      = ws + 4096;           // 32
    float* dynF    = ws + 4096 + 32;      // 50176

    mean1_kernel<<<4096, 256, 0, stream>>>(guidance, partial);
    mlp_kernel<<<1, 256, 0, stream>>>(partial, w1, b1, w2, b2, wt);
    dyn_kernel<<<(BATCH * CH * 49 + 255) / 256, 256, 0, stream>>>(wt, basis, dynF);
    conv_kernel<<<BATCH * CH, 256, 0, stream>>>(x, dynF, out);
}